// Round 1
// baseline (174.746 us; speedup 1.0000x reference)
//
#include <hip/hip_runtime.h>

// Problem constants (from reference): B=16, K=64, H=160, W=160
#define KK 64
#define HH 160
#define WW 160
#define HWPIX (HH * WW)   // 25600
#define EPSF 1e-5f

// 4 pixels per thread, two-pass recompute:
//   pass 1: per-pixel sum over the 64 gaussians (no per-k storage, low VGPR)
//   pass 2: recompute each gaussian and store float4 (16 B/lane = 1 KB/wave store)
// The quadratic exponent over 4 consecutive x-positions is updated incrementally:
//   f(m) = cb*(dx0+m)^2 + (cc*dy)*(dx0+m) + ca*dy^2, so successive diffs are
//   A1+cb, A1+3cb, A1+5cb with A1 = 2*cb*dx0 + cc*dy  (3 adds per extra pixel).
__global__ __launch_bounds__(64) void recon_confmap_kernel(
    const float* __restrict__ kp,     // [B, K, 2]  (x, y)
    const float* __restrict__ sx_p,   // scalar
    const float* __restrict__ sy_p,   // scalar
    const float* __restrict__ rho_p,  // scalar
    float* __restrict__ out)          // [B, K, H, W]
{
    __shared__ float2 skp[KK];

    const int b   = blockIdx.y;
    const int tid = threadIdx.x;

    // 64 threads load the 64 keypoints (x,y) for this batch
    skp[tid] = ((const float2*)(kp + (size_t)b * KK * 2))[tid];

    const float sx  = sx_p[0];
    const float sy  = sy_p[0];
    const float rho = rho_p[0];
    __syncthreads();

    // Fold num1 = -1/(2(1-rho^2)) and log2(e) into the quadratic coefficients.
    // out = e / (sum_k e + EPS/den)  -- den cancels against the sum.
    const float L2E   = 1.44269504088896340736f;
    const float omr2  = 1.0f - rho * rho;
    const float num1  = -0.5f / omr2;
    const float ca    = num1 / (sy * sy) * L2E;                 // * dy^2
    const float cb    = num1 / (sx * sx) * L2E;                 // * dx^2
    const float cc    = num1 * (-2.0f * rho / (sx * sy)) * L2E; // * dy*dx
    const float c2b   = 2.0f * cb;
    const float epsod = EPSF * (2.0f * 3.14159265358979323846f * sx * sy * sqrtf(omr2));

    // 4 consecutive pixels per thread; W % 4 == 0 so they never cross a row.
    const int P  = (blockIdx.x * 64 + tid) * 4;   // base pixel in [0, H*W)
    const int i  = P / WW;
    const int j0 = P - i * WW;
    const float fi = (float)i;
    const float fj = (float)j0;

    // ---- pass 1: per-pixel sums over k ----
    float s0 = 0.f, s1 = 0.f, s2 = 0.f, s3 = 0.f;
#pragma unroll
    for (int k = 0; k < KK; ++k) {
        const float dy  = fi - skp[k].y;
        const float dx  = fj - skp[k].x;
        const float tA  = cc * dy;
        const float tyy = ca * dy * dy;
        const float a0  = fmaf(tA, dx, fmaf(cb * dx, dx, tyy));
        float d = fmaf(c2b, dx, tA) + cb;        // A1 + cb
        const float a1 = a0 + d; d += c2b;
        const float a2 = a1 + d; d += c2b;
        const float a3 = a2 + d;
        s0 += __builtin_amdgcn_exp2f(a0);
        s1 += __builtin_amdgcn_exp2f(a1);
        s2 += __builtin_amdgcn_exp2f(a2);
        s3 += __builtin_amdgcn_exp2f(a3);
    }

    const float i0 = 1.0f / (s0 + epsod);
    const float i1 = 1.0f / (s1 + epsod);
    const float i2 = 1.0f / (s2 + epsod);
    const float i3 = 1.0f / (s3 + epsod);

    // Opaque copies: block CSE between the two passes (otherwise the compiler
    // may keep 256 exp results live across the loop boundary and spill).
    float fi2 = fi, fj2 = fj;
    asm("" : "+v"(fi2), "+v"(fj2));

    float* op = out + (size_t)b * KK * HWPIX + P;

    // ---- pass 2: recompute, scale, vectorized store (dwordx4) ----
#pragma unroll
    for (int k = 0; k < KK; ++k) {
        const float dy  = fi2 - skp[k].y;
        const float dx  = fj2 - skp[k].x;
        const float tA  = cc * dy;
        const float tyy = ca * dy * dy;
        const float a0  = fmaf(tA, dx, fmaf(cb * dx, dx, tyy));
        float d = fmaf(c2b, dx, tA) + cb;
        const float a1 = a0 + d; d += c2b;
        const float a2 = a1 + d; d += c2b;
        const float a3 = a2 + d;
        float4 v;
        v.x = __builtin_amdgcn_exp2f(a0) * i0;
        v.y = __builtin_amdgcn_exp2f(a1) * i1;
        v.z = __builtin_amdgcn_exp2f(a2) * i2;
        v.w = __builtin_amdgcn_exp2f(a3) * i3;
        *(float4*)(op + (size_t)k * HWPIX) = v;
    }
}

extern "C" void kernel_launch(void* const* d_in, const int* in_sizes, int n_in,
                              void* d_out, int out_size, void* d_ws, size_t ws_size,
                              hipStream_t stream) {
    const float* kp    = (const float*)d_in[0];  // keypoints [B,K,2]
    const float* sx_p  = (const float*)d_in[1];
    const float* sy_p  = (const float*)d_in[2];
    const float* rho_p = (const float*)d_in[3];
    // d_in[4] = DetectionMap: values unused by the reference (shape only)
    float* out = (float*)d_out;

    const int B = in_sizes[0] / (KK * 2);        // 16
    dim3 grid(HWPIX / (64 * 4), B);              // (100, 16), 64-thread (1-wave) blocks
    recon_confmap_kernel<<<grid, 64, 0, stream>>>(kp, sx_p, sy_p, rho_p, out);
}

// Round 2
// 168.210 us; speedup vs baseline: 1.0389x; 1.0389x over previous
//
#include <hip/hip_runtime.h>

// Problem constants (from reference): B=16, K=64, H=160, W=160
#define KK 64
#define HH 160
#define WW 160
#define HWPIX (HH * WW)   // 25600
#define EPSF 1e-5f

// Block = 256 threads (4 waves), 256 consecutive pixels per block.
//   thread t: pixel-group g = t&63 (4 consecutive pixels), k-quarter q = t>>6.
//   Wave q handles k in [16q, 16q+16)  -> per-thread work is 16 k x 4 px.
// Pass 1: partial sums over the wave's 16 gaussians; 4KB LDS reduce across
//         the 4 waves gives the full 64-k sum per pixel.
// Pass 2: recompute the 16 gaussians, scale, store float4 (16B/lane,
//         1KB per wave-store, contiguous 256-px span per k-plane).
// This keeps round-0's TLP (6400 waves = 25 waves/CU) AND round-1's wide
// stores. Incremental-quadratic update across the 4 x-positions:
//   f(m) = cb*(dx0+m)^2 + (cc*dy)*(dx0+m) + ca*dy^2 -> diffs A1+cb, A1+3cb, ...
__global__ __launch_bounds__(256) void recon_confmap_kernel(
    const float* __restrict__ kp,     // [B, K, 2]  (x, y)
    const float* __restrict__ sx_p,   // scalar
    const float* __restrict__ sy_p,   // scalar
    const float* __restrict__ rho_p,  // scalar
    float* __restrict__ out)          // [B, K, H, W]
{
    __shared__ float2 skp[KK];
    __shared__ float4 red[4][64];     // [k-quarter][pixel-group] partial sums

    const int b = blockIdx.y;
    const int t = threadIdx.x;
    const int q = t >> 6;             // wave id == k-quarter
    const int g = t & 63;             // pixel group (4 px each)

    if (t < KK) {
        skp[t] = ((const float2*)(kp + (size_t)b * KK * 2))[t];
    }

    const float sx  = sx_p[0];
    const float sy  = sy_p[0];
    const float rho = rho_p[0];
    __syncthreads();

    // Fold num1 = -1/(2(1-rho^2)) and log2(e) into the quadratic coefficients.
    // out = e / (sum_k e + EPS/den)  -- den cancels against the sum.
    const float L2E   = 1.44269504088896340736f;
    const float omr2  = 1.0f - rho * rho;
    const float num1  = -0.5f / omr2;
    const float ca    = num1 / (sy * sy) * L2E;                 // * dy^2
    const float cb    = num1 / (sx * sx) * L2E;                 // * dx^2
    const float cc    = num1 * (-2.0f * rho / (sx * sy)) * L2E; // * dy*dx
    const float c2b   = 2.0f * cb;
    const float epsod = EPSF * (2.0f * 3.14159265358979323846f * sx * sy * sqrtf(omr2));

    const int P  = blockIdx.x * 256 + g * 4;   // base pixel (W%4==0: no row cross)
    const int i  = P / WW;
    const int j0 = P - i * WW;
    const float fi = (float)i;
    const float fj = (float)j0;

    const int k0 = q * 16;

    // ---- pass 1: partial sums over this wave's 16 k's ----
    float s0 = 0.f, s1 = 0.f, s2 = 0.f, s3 = 0.f;
#pragma unroll
    for (int kk = 0; kk < 16; ++kk) {
        const float2 K2 = skp[k0 + kk];
        const float dy  = fi - K2.y;
        const float dx  = fj - K2.x;
        const float tA  = cc * dy;
        const float a0  = fmaf(tA, dx, fmaf(cb * dx, dx, ca * dy * dy));
        float d = fmaf(c2b, dx, tA) + cb;        // A1 + cb
        const float a1 = a0 + d; d += c2b;
        const float a2 = a1 + d; d += c2b;
        const float a3 = a2 + d;
        s0 += __builtin_amdgcn_exp2f(a0);
        s1 += __builtin_amdgcn_exp2f(a1);
        s2 += __builtin_amdgcn_exp2f(a2);
        s3 += __builtin_amdgcn_exp2f(a3);
    }

    red[q][g] = make_float4(s0, s1, s2, s3);
    __syncthreads();

    const float4 r0 = red[0][g];
    const float4 r1 = red[1][g];
    const float4 r2 = red[2][g];
    const float4 r3 = red[3][g];
    const float i0 = 1.0f / (r0.x + r1.x + r2.x + r3.x + epsod);
    const float i1 = 1.0f / (r0.y + r1.y + r2.y + r3.y + epsod);
    const float i2 = 1.0f / (r0.z + r1.z + r2.z + r3.z + epsod);
    const float i3 = 1.0f / (r0.w + r1.w + r2.w + r3.w + epsod);

    // Opaque copies: block CSE between the two passes (otherwise the compiler
    // may keep all 64 exp results live across the barrier and blow VGPRs).
    float fi2 = fi, fj2 = fj;
    asm("" : "+v"(fi2), "+v"(fj2));

    float* op = out + (size_t)b * KK * HWPIX + (size_t)k0 * HWPIX + P;

    // ---- pass 2: recompute this wave's 16 k's, scale, float4 store ----
#pragma unroll
    for (int kk = 0; kk < 16; ++kk) {
        const float2 K2 = skp[k0 + kk];
        const float dy  = fi2 - K2.y;
        const float dx  = fj2 - K2.x;
        const float tA  = cc * dy;
        const float a0  = fmaf(tA, dx, fmaf(cb * dx, dx, ca * dy * dy));
        float d = fmaf(c2b, dx, tA) + cb;
        const float a1 = a0 + d; d += c2b;
        const float a2 = a1 + d; d += c2b;
        const float a3 = a2 + d;
        float4 v;
        v.x = __builtin_amdgcn_exp2f(a0) * i0;
        v.y = __builtin_amdgcn_exp2f(a1) * i1;
        v.z = __builtin_amdgcn_exp2f(a2) * i2;
        v.w = __builtin_amdgcn_exp2f(a3) * i3;
        *(float4*)(op + (size_t)kk * HWPIX) = v;
    }
}

extern "C" void kernel_launch(void* const* d_in, const int* in_sizes, int n_in,
                              void* d_out, int out_size, void* d_ws, size_t ws_size,
                              hipStream_t stream) {
    const float* kp    = (const float*)d_in[0];  // keypoints [B,K,2]
    const float* sx_p  = (const float*)d_in[1];
    const float* sy_p  = (const float*)d_in[2];
    const float* rho_p = (const float*)d_in[3];
    // d_in[4] = DetectionMap: values unused by the reference (shape only)
    float* out = (float*)d_out;

    const int B = in_sizes[0] / (KK * 2);        // 16
    dim3 grid(HWPIX / 256, B);                   // (100, 16), 256-thread blocks
    recon_confmap_kernel<<<grid, 256, 0, stream>>>(kp, sx_p, sy_p, rho_p, out);
}

// Round 3
// 167.815 us; speedup vs baseline: 1.0413x; 1.0024x over previous
//
#include <hip/hip_runtime.h>

// Problem constants (from reference): B=16, K=64, H=160, W=160
#define KK 64
#define HH 160
#define WW 160
#define HWPIX (HH * WW)   // 25600
#define EPSF 1e-5f

typedef float v4f __attribute__((ext_vector_type(4)));

// Identical structure to round 2 (256-thread blocks, wave q owns k in
// [16q,16q+16), LDS reduce for the denominator, recompute pass for stores),
// with ONE change: stores are nontemporal (nt bit -> bypass/stream L2).
// The output (100 MiB) sweeps the 32 MiB L2 every iteration; if write-allocate
// + dirty eviction was throttling the store path, nt removes it.
__global__ __launch_bounds__(256) void recon_confmap_kernel(
    const float* __restrict__ kp,     // [B, K, 2]  (x, y)
    const float* __restrict__ sx_p,   // scalar
    const float* __restrict__ sy_p,   // scalar
    const float* __restrict__ rho_p,  // scalar
    float* __restrict__ out)          // [B, K, H, W]
{
    __shared__ float2 skp[KK];
    __shared__ float4 red[4][64];     // [k-quarter][pixel-group] partial sums

    const int b = blockIdx.y;
    const int t = threadIdx.x;
    const int q = t >> 6;             // wave id == k-quarter
    const int g = t & 63;             // pixel group (4 px each)

    if (t < KK) {
        skp[t] = ((const float2*)(kp + (size_t)b * KK * 2))[t];
    }

    const float sx  = sx_p[0];
    const float sy  = sy_p[0];
    const float rho = rho_p[0];
    __syncthreads();

    // Fold num1 = -1/(2(1-rho^2)) and log2(e) into the quadratic coefficients.
    // out = e / (sum_k e + EPS/den)  -- den cancels against the sum.
    const float L2E   = 1.44269504088896340736f;
    const float omr2  = 1.0f - rho * rho;
    const float num1  = -0.5f / omr2;
    const float ca    = num1 / (sy * sy) * L2E;                 // * dy^2
    const float cb    = num1 / (sx * sx) * L2E;                 // * dx^2
    const float cc    = num1 * (-2.0f * rho / (sx * sy)) * L2E; // * dy*dx
    const float c2b   = 2.0f * cb;
    const float epsod = EPSF * (2.0f * 3.14159265358979323846f * sx * sy * sqrtf(omr2));

    const int P  = blockIdx.x * 256 + g * 4;   // base pixel (W%4==0: no row cross)
    const int i  = P / WW;
    const int j0 = P - i * WW;
    const float fi = (float)i;
    const float fj = (float)j0;

    const int k0 = q * 16;

    // ---- pass 1: partial sums over this wave's 16 k's ----
    float s0 = 0.f, s1 = 0.f, s2 = 0.f, s3 = 0.f;
#pragma unroll
    for (int kk = 0; kk < 16; ++kk) {
        const float2 K2 = skp[k0 + kk];
        const float dy  = fi - K2.y;
        const float dx  = fj - K2.x;
        const float tA  = cc * dy;
        const float a0  = fmaf(tA, dx, fmaf(cb * dx, dx, ca * dy * dy));
        float d = fmaf(c2b, dx, tA) + cb;        // A1 + cb
        const float a1 = a0 + d; d += c2b;
        const float a2 = a1 + d; d += c2b;
        const float a3 = a2 + d;
        s0 += __builtin_amdgcn_exp2f(a0);
        s1 += __builtin_amdgcn_exp2f(a1);
        s2 += __builtin_amdgcn_exp2f(a2);
        s3 += __builtin_amdgcn_exp2f(a3);
    }

    red[q][g] = make_float4(s0, s1, s2, s3);
    __syncthreads();

    const float4 r0 = red[0][g];
    const float4 r1 = red[1][g];
    const float4 r2 = red[2][g];
    const float4 r3 = red[3][g];
    const float i0 = 1.0f / (r0.x + r1.x + r2.x + r3.x + epsod);
    const float i1 = 1.0f / (r0.y + r1.y + r2.y + r3.y + epsod);
    const float i2 = 1.0f / (r0.z + r1.z + r2.z + r3.z + epsod);
    const float i3 = 1.0f / (r0.w + r1.w + r2.w + r3.w + epsod);

    // Opaque copies: block CSE between the two passes (otherwise the compiler
    // may keep all 64 exp results live across the barrier and blow VGPRs).
    float fi2 = fi, fj2 = fj;
    asm("" : "+v"(fi2), "+v"(fj2));

    float* op = out + (size_t)b * KK * HWPIX + (size_t)k0 * HWPIX + P;

    // ---- pass 2: recompute this wave's 16 k's, scale, nontemporal float4 store ----
#pragma unroll
    for (int kk = 0; kk < 16; ++kk) {
        const float2 K2 = skp[k0 + kk];
        const float dy  = fi2 - K2.y;
        const float dx  = fj2 - K2.x;
        const float tA  = cc * dy;
        const float a0  = fmaf(tA, dx, fmaf(cb * dx, dx, ca * dy * dy));
        float d = fmaf(c2b, dx, tA) + cb;
        const float a1 = a0 + d; d += c2b;
        const float a2 = a1 + d; d += c2b;
        const float a3 = a2 + d;
        v4f v;
        v.x = __builtin_amdgcn_exp2f(a0) * i0;
        v.y = __builtin_amdgcn_exp2f(a1) * i1;
        v.z = __builtin_amdgcn_exp2f(a2) * i2;
        v.w = __builtin_amdgcn_exp2f(a3) * i3;
        __builtin_nontemporal_store(v, (v4f*)(op + (size_t)kk * HWPIX));
    }
}

extern "C" void kernel_launch(void* const* d_in, const int* in_sizes, int n_in,
                              void* d_out, int out_size, void* d_ws, size_t ws_size,
                              hipStream_t stream) {
    const float* kp    = (const float*)d_in[0];  // keypoints [B,K,2]
    const float* sx_p  = (const float*)d_in[1];
    const float* sy_p  = (const float*)d_in[2];
    const float* rho_p = (const float*)d_in[3];
    // d_in[4] = DetectionMap: values unused by the reference (shape only)
    float* out = (float*)d_out;

    const int B = in_sizes[0] / (KK * 2);        // 16
    dim3 grid(HWPIX / 256, B);                   // (100, 16), 256-thread blocks
    recon_confmap_kernel<<<grid, 256, 0, stream>>>(kp, sx_p, sy_p, rho_p, out);
}